// Round 4
// baseline (381.456 us; speedup 1.0000x reference)
//
#include <hip/hip_runtime.h>
#include <hip/hip_bf16.h>
#include <hip/hip_cooperative_groups.h>
#include <stdint.h>

#define IMG   224
#define OUTD  256
#define BATCH 256
#define JD    25
#define TD    64
#define MIDJ  12
#define BOXR  20

// workspace layout (bytes)
//   P     : bf16 [224][225][256]  = 25,804,800
//   runs  : u32  [256][224][32]   =  7,340,032   (<=12 entries used per (b,x))
//   part  : f32  [256][8][256]    =  2,097,152
//   cnt   : u8   [256][224]       =     57,344
#define OFF_RUNS 25804800u
#define OFF_PART 33144832u
#define OFF_CNT  35241984u

// ================= KA: fused wpref (blocks 0..1791) + boxes (1792..2047) =====
// wpref block mapping: id = ((x%28)*8 + oc)*8 + x/28  ->  id%8 == x/28, so
// (under round-robin dispatch) the XCD that writes P slice s is the XCD whose
// KB blocks read it. boxes blocks ride at the tail and overlap K1's streaming.
__global__ void KA(const float* __restrict__ W, __hip_bfloat16* __restrict__ P,
                   const float* __restrict__ skel, uint32_t* __restrict__ runs,
                   uint8_t* __restrict__ cnt) {
    const int id  = blockIdx.x;
    const int tid = threadIdx.x;

    __shared__ float lds[32][225];      // wpref: [o_local][y], pad 225 bank-safe
    __shared__ float carry[8][32];
    __shared__ int s_px[JD], s_ylo[JD], s_yhi[JD];

    if (id < 1792) {
        // ---------------- wpref ----------------
        const int xcd = id & 7;
        const int g   = id >> 3;        // 0..223
        const int oc  = g & 7;
        const int xi  = g >> 3;         // 0..27
        const int x   = xcd * 28 + xi;
        const int o0  = oc * 32;

        #pragma unroll
        for (int it = 0; it < 28; ++it) {
            const int k = it * 256 + tid;   // 0..7167 = 32*224
            const int r = k / 224;
            const int y = k - r * 224;
            lds[r][y] = W[(size_t)(o0 + r) * (IMG * IMG) + (size_t)x * IMG + y];
        }
        __syncthreads();

        const int ol  = tid & 31;
        const int seg = tid >> 5;       // 0..7
        const int y0  = seg * 28;

        float ssum = 0.0f;
        #pragma unroll
        for (int i = 0; i < 28; ++i) ssum += lds[ol][y0 + i];
        carry[seg][ol] = ssum;
        __syncthreads();

        float s = 0.0f;
        for (int s2 = 0; s2 < seg; ++s2) s += carry[s2][ol];

        __hip_bfloat16* p = P + ((size_t)x * 225) * 256 + o0 + ol;
        if (seg == 0) p[0] = __float2bfloat16(0.0f);
        #pragma unroll
        for (int i = 0; i < 28; ++i) {
            s += lds[ol][y0 + i];
            p[(size_t)(y0 + i + 1) * 256] = __float2bfloat16(s);
        }
        return;
    }

    // ---------------- boxes/runs ----------------
    const int b = id - 1792;
    const int wave = tid >> 6;
    const int t = tid & 63;

    const float* sb = skel + (size_t)b * JD * TD * 3;
    const float mx = sb[(MIDJ * TD + t) * 3 + 0];
    const float my = sb[(MIDJ * TD + t) * 3 + 1];
    const float mz = sb[(MIDJ * TD + t) * 3 + 2];

    for (int j = wave; j < JD; j += 4) {
        const float ax = sb[(j * TD + t) * 3 + 0];
        const float ay = sb[(j * TD + t) * 3 + 1];
        const float az = sb[(j * TD + t) * 3 + 2];
        const float dx = ax - mx, dy = ay - my, dz = az - mz;
        // match numpy: no fma contraction, left-to-right adds, IEEE sqrt
        const float d2 = __fadd_rn(__fadd_rn(__fmul_rn(dx, dx), __fmul_rn(dy, dy)),
                                   __fmul_rn(dz, dz));
        float bd = sqrtf(d2);
        int   bi = t;
        #pragma unroll
        for (int off = 1; off < 64; off <<= 1) {
            const float od = __shfl_xor(bd, off);
            const int   oi = __shfl_xor(bi, off);
            if (od > bd || (od == bd && oi < bi)) { bd = od; bi = oi; }
        }
        if (t == 0) {
            const float ptx = sb[(j * TD + bi) * 3 + 0];
            const float pty = sb[(j * TD + bi) * 3 + 1];
            const int px = (int)(ptx * 224.0f);
            const int py = (int)(pty * 224.0f);
            s_px[j]  = px;
            s_ylo[j] = (py < BOXR) ? 0 : (py - BOXR);
            s_yhi[j] = (py > IMG - BOXR) ? IMG : (py + BOXR);
        }
    }
    __syncthreads();

    const int x = tid;
    if (x >= IMG) return;

    unsigned long long m0 = 0, m1 = 0, m2 = 0, m3 = 0;
    for (int j = 0; j < JD; ++j) {
        if (j == MIDJ) continue;
        const int px = s_px[j];
        if (x >= px - BOXR && x < px + BOXR) {
            const int lo = s_ylo[j], hi = s_yhi[j];
            auto setw = [&](unsigned long long& mw, int wbase) {
                int l = lo - wbase; int h = hi - wbase;
                l = l < 0 ? 0 : l; h = h > 64 ? 64 : h;
                if (l < h) {
                    unsigned long long msk =
                        (h - l == 64) ? ~0ull : ((((1ull << (h - l)) - 1ull)) << l);
                    mw |= msk;
                }
            };
            setw(m0, 0); setw(m1, 64); setw(m2, 128); setw(m3, 192);
        }
    }

    uint32_t* rb = runs + ((size_t)b * IMG + x) * 32;
    int n = 0, start = -1;
    auto scanw = [&](unsigned long long bits, int wbase) {
        int pos = 0;
        while (pos < 64) {
            if (start < 0) {
                const unsigned long long tt = bits >> pos;
                if (!tt) return;
                pos += __builtin_ctzll(tt);
                start = wbase + pos;
            } else {
                const unsigned long long tt = (~bits) >> pos;
                if (!tt) return;
                pos += __builtin_ctzll(tt);
                rb[n] = (uint32_t)start | ((uint32_t)(wbase + pos) << 8);
                ++n; start = -1;
            }
        }
    };
    scanw(m0, 0); scanw(m1, 64); scanw(m2, 128); scanw(m3, 192);
    if (start >= 0) { rb[n] = (uint32_t)start | (224u << 8); ++n; }
    cnt[(size_t)b * IMG + x] = (uint8_t)n;
}

// ============ KB (cooperative): accum (all 2048 blocks) + grid sync + final ==
// accum: three-phase (counts -> flat LDS list -> streamed endpoint loads).
// blockIdx = b*8+s puts x-slice s on XCD s (3.2MB P slice fits 4MB L2).
// After grid.sync, blocks 0..255 apply out = rgb * (bias + sum part).
__global__ void KB(const uint32_t* __restrict__ runs, const uint8_t* __restrict__ cnt,
                   const uint32_t* __restrict__ P32, float* __restrict__ part,
                   const float* __restrict__ rgb, const float* __restrict__ bias,
                   float* __restrict__ out) {
    const int b = blockIdx.x >> 3;
    const int s = blockIdx.x & 7;
    const int tid = threadIdx.x;    // 0..127 -> outputs 2*tid, 2*tid+1
    const int x0 = s * 28;

    __shared__ uint8_t  scnt[28];
    __shared__ uint16_t soff[29];
    __shared__ uint32_t slist[28 * 12];

    if (tid < 28) scnt[tid] = cnt[(size_t)b * IMG + x0 + tid];
    __syncthreads();
    if (tid == 0) {
        uint16_t acc = 0;
        #pragma unroll
        for (int i = 0; i < 28; ++i) { soff[i] = acc; acc += scnt[i]; }
        soff[28] = acc;
    }
    __syncthreads();

    for (int e = tid; e < 28 * 12; e += 128) {
        const int xl = e / 12;
        const int j  = e - xl * 12;
        if (j < (int)scnt[xl]) {
            const uint32_t raw = runs[((size_t)b * IMG + x0 + xl) * 32 + j]; // bits 0..16
            slist[soff[xl] + j] = raw | ((uint32_t)xl << 17);
        }
    }
    __syncthreads();

    const int total = soff[28];
    float a0 = 0.0f, a1 = 0.0f;
    for (int i = 0; i < total; ++i) {
        const uint32_t e = slist[i];                  // LDS broadcast
        const int xl = (int)(e >> 17);
        const int a  = (int)(e & 255u);
        const int c  = (int)((e >> 8) & 511u);
        const uint32_t* px = P32 + (size_t)(x0 + xl) * 225 * 128 + tid;
        const uint32_t va = px[(size_t)a * 128];
        const uint32_t vc = px[(size_t)c * 128];
        a0 += __uint_as_float(vc << 16) - __uint_as_float(va << 16);
        a1 += __uint_as_float(vc & 0xffff0000u) - __uint_as_float(va & 0xffff0000u);
    }

    float* pp = part + (((size_t)b * 8 + s) * 256) + (size_t)tid * 2;
    pp[0] = a0;
    pp[1] = a1;

    __threadfence();                      // device-scope release (L2 writeback)
    cooperative_groups::this_grid().sync();

    // ---------------- final: blocks 0..255 ----------------
    if (blockIdx.x < 256) {
        const int b2 = blockIdx.x;
        #pragma unroll
        for (int oo = 0; oo < 2; ++oo) {
            const int o = tid + oo * 128;
            float m = bias[o];
            #pragma unroll
            for (int s2 = 0; s2 < 8; ++s2)
                m += part[(((size_t)b2 * 8 + s2) * 256) + o];
            out[(size_t)b2 * 256 + o] = rgb[(size_t)b2 * 256 + o] * m;
        }
    }
}

extern "C" void kernel_launch(void* const* d_in, const int* in_sizes, int n_in,
                              void* d_out, int out_size, void* d_ws, size_t ws_size,
                              hipStream_t stream) {
    const float* rgb  = (const float*)d_in[0];
    const float* skel = (const float*)d_in[1];
    const float* W    = (const float*)d_in[2];
    const float* bias = (const float*)d_in[3];
    float* out = (float*)d_out;

    uint8_t* ws = (uint8_t*)d_ws;
    __hip_bfloat16* P = (__hip_bfloat16*)(ws);
    uint32_t* runs = (uint32_t*)(ws + OFF_RUNS);
    float* part = (float*)(ws + OFF_PART);
    uint8_t* cnt = (uint8_t*)(ws + OFF_CNT);

    KA<<<dim3(2048), dim3(256), 0, stream>>>(W, P, skel, runs, cnt);

    const uint32_t* P32 = (const uint32_t*)P;
    const uint8_t* cntc = cnt;
    const uint32_t* runsc = runs;
    void* args[] = { (void*)&runsc, (void*)&cntc, (void*)&P32, (void*)&part,
                     (void*)&rgb, (void*)&bias, (void*)&out };
    hipLaunchCooperativeKernel((void*)KB, dim3(2048), dim3(128), args, 0, stream);
}

// Round 5
// 136.766 us; speedup vs baseline: 2.7891x; 2.7891x over previous
//
#include <hip/hip_runtime.h>
#include <hip/hip_bf16.h>
#include <stdint.h>

#define IMG   224
#define OUTD  256
#define BATCH 256
#define JD    25
#define TD    64
#define MIDJ  12
#define BOXR  20

// workspace layout (bytes)
//   P     : bf16 [224][225][256]  = 25,804,800
//   runs  : u32  [256][224][32]   =  7,340,032   (<=12 entries used per (b,x))
//   part  : f32  [256][8][256]    =  2,097,152
//   cnt   : u8   [256][224]       =     57,344
//   ctr   : u32  [256]            =      1,024   (zeroed by KA every call)
#define OFF_RUNS 25804800u
#define OFF_PART 33144832u
#define OFF_CNT  35241984u
#define OFF_CTR  35299328u

// ================= KA: fused wpref (blocks 0..1791) + boxes (1792..2047) =====
// wpref block mapping: id%8 == x/28 == slice, so (round-robin dispatch) the
// XCD that writes P slice s is the XCD whose KB2 slice-s blocks read it.
// W loads are nontemporal so the W stream (6.4MB/XCD) doesn't evict the P
// slice (3.2MB) from that XCD's 4MB L2.
__global__ void KA(const float* __restrict__ W, __hip_bfloat16* __restrict__ P,
                   const float* __restrict__ skel, uint32_t* __restrict__ runs,
                   uint8_t* __restrict__ cnt, uint32_t* __restrict__ ctr) {
    const int id  = blockIdx.x;
    const int tid = threadIdx.x;

    __shared__ float lds[32][225];      // wpref: [o_local][y], pad 225 bank-safe
    __shared__ float carry[8][32];
    __shared__ int s_px[JD], s_ylo[JD], s_yhi[JD];

    if (id < 1792) {
        // ---------------- wpref ----------------
        const int xcd = id & 7;
        const int g   = id >> 3;        // 0..223
        const int oc  = g & 7;
        const int xi  = g >> 3;         // 0..27
        const int x   = xcd * 28 + xi;
        const int o0  = oc * 32;

        #pragma unroll
        for (int it = 0; it < 28; ++it) {
            const int k = it * 256 + tid;   // 0..7167 = 32*224
            const int r = k / 224;
            const int y = k - r * 224;
            lds[r][y] = __builtin_nontemporal_load(
                &W[(size_t)(o0 + r) * (IMG * IMG) + (size_t)x * IMG + y]);
        }
        __syncthreads();

        const int ol  = tid & 31;
        const int seg = tid >> 5;       // 0..7
        const int y0  = seg * 28;

        float ssum = 0.0f;
        #pragma unroll
        for (int i = 0; i < 28; ++i) ssum += lds[ol][y0 + i];
        carry[seg][ol] = ssum;
        __syncthreads();

        float s = 0.0f;
        for (int s2 = 0; s2 < seg; ++s2) s += carry[s2][ol];

        __hip_bfloat16* p = P + ((size_t)x * 225) * 256 + o0 + ol;
        if (seg == 0) p[0] = __float2bfloat16(0.0f);
        #pragma unroll
        for (int i = 0; i < 28; ++i) {
            s += lds[ol][y0 + i];
            p[(size_t)(y0 + i + 1) * 256] = __float2bfloat16(s);
        }
        return;
    }

    // ---------------- boxes/runs (one block per batch) ----------------
    const int b = id - 1792;
    if (tid == 0) ctr[b] = 0;           // reset done-counter for KB2 (every call)
    const int wave = tid >> 6;
    const int t = tid & 63;

    const float* sb = skel + (size_t)b * JD * TD * 3;
    const float mx = sb[(MIDJ * TD + t) * 3 + 0];
    const float my = sb[(MIDJ * TD + t) * 3 + 1];
    const float mz = sb[(MIDJ * TD + t) * 3 + 2];

    for (int j = wave; j < JD; j += 4) {
        const float ax = sb[(j * TD + t) * 3 + 0];
        const float ay = sb[(j * TD + t) * 3 + 1];
        const float az = sb[(j * TD + t) * 3 + 2];
        const float dx = ax - mx, dy = ay - my, dz = az - mz;
        // match numpy: no fma contraction, left-to-right adds, IEEE sqrt
        const float d2 = __fadd_rn(__fadd_rn(__fmul_rn(dx, dx), __fmul_rn(dy, dy)),
                                   __fmul_rn(dz, dz));
        float bd = sqrtf(d2);
        int   bi = t;
        #pragma unroll
        for (int off = 1; off < 64; off <<= 1) {
            const float od = __shfl_xor(bd, off);
            const int   oi = __shfl_xor(bi, off);
            if (od > bd || (od == bd && oi < bi)) { bd = od; bi = oi; }
        }
        if (t == 0) {
            const float ptx = sb[(j * TD + bi) * 3 + 0];
            const float pty = sb[(j * TD + bi) * 3 + 1];
            const int px = (int)(ptx * 224.0f);
            const int py = (int)(pty * 224.0f);
            s_px[j]  = px;
            s_ylo[j] = (py < BOXR) ? 0 : (py - BOXR);
            s_yhi[j] = (py > IMG - BOXR) ? IMG : (py + BOXR);
        }
    }
    __syncthreads();

    const int x = tid;
    if (x >= IMG) return;

    unsigned long long m0 = 0, m1 = 0, m2 = 0, m3 = 0;
    for (int j = 0; j < JD; ++j) {
        if (j == MIDJ) continue;
        const int px = s_px[j];
        if (x >= px - BOXR && x < px + BOXR) {
            const int lo = s_ylo[j], hi = s_yhi[j];
            auto setw = [&](unsigned long long& mw, int wbase) {
                int l = lo - wbase; int h = hi - wbase;
                l = l < 0 ? 0 : l; h = h > 64 ? 64 : h;
                if (l < h) {
                    unsigned long long msk =
                        (h - l == 64) ? ~0ull : ((((1ull << (h - l)) - 1ull)) << l);
                    mw |= msk;
                }
            };
            setw(m0, 0); setw(m1, 64); setw(m2, 128); setw(m3, 192);
        }
    }

    uint32_t* rb = runs + ((size_t)b * IMG + x) * 32;
    int n = 0, start = -1;
    auto scanw = [&](unsigned long long bits, int wbase) {
        int pos = 0;
        while (pos < 64) {
            if (start < 0) {
                const unsigned long long tt = bits >> pos;
                if (!tt) return;
                pos += __builtin_ctzll(tt);
                start = wbase + pos;
            } else {
                const unsigned long long tt = (~bits) >> pos;
                if (!tt) return;
                pos += __builtin_ctzll(tt);
                rb[n] = (uint32_t)start | ((uint32_t)(wbase + pos) << 8);
                ++n; start = -1;
            }
        }
    };
    scanw(m0, 0); scanw(m1, 64); scanw(m2, 128); scanw(m3, 192);
    if (start >= 0) { rb[n] = (uint32_t)start | (224u << 8); ++n; }
    cnt[(size_t)b * IMG + x] = (uint8_t)n;
}

// ====== KB2: accum (2048 blocks, slice s -> XCD s) + last-block final ========
// Three-phase accum (counts -> flat LDS list -> streamed endpoint loads) to
// keep the dependent-load chain depth at 3. The 8th block to finish a batch
// (device-scope atomic) applies out = rgb * (bias + sum part) — deterministic
// because the summation order is fixed regardless of arrival order.
__global__ void KB2(const uint32_t* __restrict__ runs, const uint8_t* __restrict__ cnt,
                    const uint32_t* __restrict__ P32, float* __restrict__ part,
                    uint32_t* __restrict__ ctr,
                    const float* __restrict__ rgb, const float* __restrict__ bias,
                    float* __restrict__ out) {
    const int b = blockIdx.x >> 3;
    const int s = blockIdx.x & 7;
    const int tid = threadIdx.x;    // 0..127 -> outputs 2*tid, 2*tid+1
    const int x0 = s * 28;

    __shared__ uint8_t  scnt[28];
    __shared__ uint16_t soff[29];
    __shared__ uint32_t slist[28 * 12];
    __shared__ int s_done;

    if (tid < 28) scnt[tid] = cnt[(size_t)b * IMG + x0 + tid];
    __syncthreads();
    if (tid == 0) {
        uint16_t acc = 0;
        #pragma unroll
        for (int i = 0; i < 28; ++i) { soff[i] = acc; acc += scnt[i]; }
        soff[28] = acc;
    }
    __syncthreads();

    for (int e = tid; e < 28 * 12; e += 128) {
        const int xl = e / 12;
        const int j  = e - xl * 12;
        if (j < (int)scnt[xl]) {
            const uint32_t raw = runs[((size_t)b * IMG + x0 + xl) * 32 + j]; // bits 0..16
            slist[soff[xl] + j] = raw | ((uint32_t)xl << 17);
        }
    }
    __syncthreads();

    const int total = soff[28];
    float a0 = 0.0f, a1 = 0.0f;
    for (int i = 0; i < total; ++i) {
        const uint32_t e = slist[i];                  // LDS broadcast
        const int xl = (int)(e >> 17);
        const int a  = (int)(e & 255u);
        const int c  = (int)((e >> 8) & 511u);
        const uint32_t* px = P32 + (size_t)(x0 + xl) * 225 * 128 + tid;
        const uint32_t va = px[(size_t)a * 128];
        const uint32_t vc = px[(size_t)c * 128];
        a0 += __uint_as_float(vc << 16) - __uint_as_float(va << 16);
        a1 += __uint_as_float(vc & 0xffff0000u) - __uint_as_float(va & 0xffff0000u);
    }

    float* pp = part + (((size_t)b * 8 + s) * 256) + (size_t)tid * 2;
    pp[0] = a0;
    pp[1] = a1;

    // release our part slice, count arrivals for this batch
    __threadfence();
    if (tid == 0) s_done = (int)atomicAdd(&ctr[b], 1u);
    __syncthreads();
    if (s_done != 7) return;

    // we are the 8th (last) block for batch b: acquire, then final multiply
    __threadfence();
    #pragma unroll
    for (int oo = 0; oo < 2; ++oo) {
        const int o = tid + oo * 128;
        float m = bias[o];
        #pragma unroll
        for (int s2 = 0; s2 < 8; ++s2)
            m += part[(((size_t)b * 8 + s2) * 256) + o];
        out[(size_t)b * 256 + o] = rgb[(size_t)b * 256 + o] * m;
    }
}

extern "C" void kernel_launch(void* const* d_in, const int* in_sizes, int n_in,
                              void* d_out, int out_size, void* d_ws, size_t ws_size,
                              hipStream_t stream) {
    const float* rgb  = (const float*)d_in[0];
    const float* skel = (const float*)d_in[1];
    const float* W    = (const float*)d_in[2];
    const float* bias = (const float*)d_in[3];
    float* out = (float*)d_out;

    uint8_t* ws = (uint8_t*)d_ws;
    __hip_bfloat16* P = (__hip_bfloat16*)(ws);
    uint32_t* runs = (uint32_t*)(ws + OFF_RUNS);
    float* part = (float*)(ws + OFF_PART);
    uint8_t* cnt = (uint8_t*)(ws + OFF_CNT);
    uint32_t* ctr = (uint32_t*)(ws + OFF_CTR);

    KA<<<dim3(2048), dim3(256), 0, stream>>>(W, P, skel, runs, cnt, ctr);
    KB2<<<dim3(2048), dim3(128), 0, stream>>>(runs, cnt, (const uint32_t*)P, part,
                                              ctr, rgb, bias, out);
}

// Round 6
// 45.429 us; speedup vs baseline: 8.3967x; 3.0105x over previous
//
#include <hip/hip_runtime.h>
#include <hip/hip_bf16.h>
#include <stdint.h>

#define IMG   224
#define OUTD  256
#define BATCH 256
#define JD    25
#define TD    64
#define MIDJ  12
#define BOXR  20

// workspace layout (bytes)
//   P     : bf16 [224][225][256]  = 25,804,800
//   runs  : u32  [256][224][32]   =  7,340,032   (<=12 entries used per (b,x))
//   part  : f32  [256][8][256]    =  2,097,152
//   cnt   : u8   [256][224]       =     57,344
#define OFF_RUNS 25804800u
#define OFF_PART 33144832u
#define OFF_CNT  35241984u

// NOTE (learned round 4/5): NO device-scope fences (__threadfence / coop grid
// sync) inside kernels — on gfx950 an agent-scope release forces an L2
// writeback per issuing block (per-XCD L2s are non-coherent), which evicted P
// and cost 70-300us. Kernel boundaries give the same visibility with ONE
// amortized L2 flush per XCD.

// ================= KA: fused wpref (blocks 0..1791) + boxes (1792..2047) =====
// wpref block mapping: id%8 == x/28 == slice s, so (round-robin dispatch) the
// XCD that writes P slice s is the XCD whose k_accum slice-s blocks read it.
// W loads are nontemporal: W (51MB) is read exactly once, don't pollute L2.
__global__ void KA(const float* __restrict__ W, __hip_bfloat16* __restrict__ P,
                   const float* __restrict__ skel, uint32_t* __restrict__ runs,
                   uint8_t* __restrict__ cnt) {
    const int id  = blockIdx.x;
    const int tid = threadIdx.x;

    __shared__ float lds[32][225];      // wpref: [o_local][y], pad 225 bank-safe
    __shared__ float carry[8][32];
    __shared__ int s_px[JD], s_ylo[JD], s_yhi[JD];

    if (id < 1792) {
        // ---------------- wpref ----------------
        const int xcd = id & 7;
        const int g   = id >> 3;        // 0..223
        const int oc  = g & 7;
        const int xi  = g >> 3;         // 0..27
        const int x   = xcd * 28 + xi;
        const int o0  = oc * 32;

        #pragma unroll
        for (int it = 0; it < 28; ++it) {
            const int k = it * 256 + tid;   // 0..7167 = 32*224
            const int r = k / 224;
            const int y = k - r * 224;
            lds[r][y] = __builtin_nontemporal_load(
                &W[(size_t)(o0 + r) * (IMG * IMG) + (size_t)x * IMG + y]);
        }
        __syncthreads();

        const int ol  = tid & 31;
        const int seg = tid >> 5;       // 0..7
        const int y0  = seg * 28;

        float ssum = 0.0f;
        #pragma unroll
        for (int i = 0; i < 28; ++i) ssum += lds[ol][y0 + i];
        carry[seg][ol] = ssum;
        __syncthreads();

        float s = 0.0f;
        for (int s2 = 0; s2 < seg; ++s2) s += carry[s2][ol];

        __hip_bfloat16* p = P + ((size_t)x * 225) * 256 + o0 + ol;
        if (seg == 0) p[0] = __float2bfloat16(0.0f);
        #pragma unroll
        for (int i = 0; i < 28; ++i) {
            s += lds[ol][y0 + i];
            p[(size_t)(y0 + i + 1) * 256] = __float2bfloat16(s);
        }
        return;
    }

    // ---------------- boxes/runs (one block per batch) ----------------
    const int b = id - 1792;
    const int wave = tid >> 6;
    const int t = tid & 63;

    const float* sb = skel + (size_t)b * JD * TD * 3;
    const float mx = sb[(MIDJ * TD + t) * 3 + 0];
    const float my = sb[(MIDJ * TD + t) * 3 + 1];
    const float mz = sb[(MIDJ * TD + t) * 3 + 2];

    for (int j = wave; j < JD; j += 4) {
        const float ax = sb[(j * TD + t) * 3 + 0];
        const float ay = sb[(j * TD + t) * 3 + 1];
        const float az = sb[(j * TD + t) * 3 + 2];
        const float dx = ax - mx, dy = ay - my, dz = az - mz;
        // match numpy: no fma contraction, left-to-right adds, IEEE sqrt
        const float d2 = __fadd_rn(__fadd_rn(__fmul_rn(dx, dx), __fmul_rn(dy, dy)),
                                   __fmul_rn(dz, dz));
        float bd = sqrtf(d2);
        int   bi = t;
        #pragma unroll
        for (int off = 1; off < 64; off <<= 1) {
            const float od = __shfl_xor(bd, off);
            const int   oi = __shfl_xor(bi, off);
            if (od > bd || (od == bd && oi < bi)) { bd = od; bi = oi; }
        }
        if (t == 0) {
            const float ptx = sb[(j * TD + bi) * 3 + 0];
            const float pty = sb[(j * TD + bi) * 3 + 1];
            const int px = (int)(ptx * 224.0f);
            const int py = (int)(pty * 224.0f);
            s_px[j]  = px;
            s_ylo[j] = (py < BOXR) ? 0 : (py - BOXR);
            s_yhi[j] = (py > IMG - BOXR) ? IMG : (py + BOXR);
        }
    }
    __syncthreads();

    const int x = tid;
    if (x >= IMG) return;

    unsigned long long m0 = 0, m1 = 0, m2 = 0, m3 = 0;
    for (int j = 0; j < JD; ++j) {
        if (j == MIDJ) continue;
        const int px = s_px[j];
        if (x >= px - BOXR && x < px + BOXR) {
            const int lo = s_ylo[j], hi = s_yhi[j];
            auto setw = [&](unsigned long long& mw, int wbase) {
                int l = lo - wbase; int h = hi - wbase;
                l = l < 0 ? 0 : l; h = h > 64 ? 64 : h;
                if (l < h) {
                    unsigned long long msk =
                        (h - l == 64) ? ~0ull : ((((1ull << (h - l)) - 1ull)) << l);
                    mw |= msk;
                }
            };
            setw(m0, 0); setw(m1, 64); setw(m2, 128); setw(m3, 192);
        }
    }

    uint32_t* rb = runs + ((size_t)b * IMG + x) * 32;
    int n = 0, start = -1;
    auto scanw = [&](unsigned long long bits, int wbase) {
        int pos = 0;
        while (pos < 64) {
            if (start < 0) {
                const unsigned long long tt = bits >> pos;
                if (!tt) return;
                pos += __builtin_ctzll(tt);
                start = wbase + pos;
            } else {
                const unsigned long long tt = (~bits) >> pos;
                if (!tt) return;
                pos += __builtin_ctzll(tt);
                rb[n] = (uint32_t)start | ((uint32_t)(wbase + pos) << 8);
                ++n; start = -1;
            }
        }
    };
    scanw(m0, 0); scanw(m1, 64); scanw(m2, 128); scanw(m3, 192);
    if (start >= 0) { rb[n] = (uint32_t)start | (224u << 8); ++n; }
    cnt[(size_t)b * IMG + x] = (uint8_t)n;
}

// ---------------- K3: accumulate run endpoint diffs over prefix table --------
// Three-phase (counts -> flat LDS list -> streamed endpoint loads), chain
// depth 3. Event loop 2-way unrolled with independent accumulators so >=4
// endpoint loads are in flight per wave (round-5 VGPR=16 showed ~1 pair).
// blockIdx = b*8+s puts x-slice s on XCD s, matching KA's P placement.
__global__ void k_accum(const uint32_t* __restrict__ runs,
                        const uint8_t* __restrict__ cnt,
                        const uint32_t* __restrict__ P32,   // P viewed as bf16x2
                        float* __restrict__ part) {
    const int b = blockIdx.x >> 3;
    const int s = blockIdx.x & 7;
    const int tid = threadIdx.x;    // 0..127 -> outputs 2*tid, 2*tid+1
    const int x0 = s * 28;

    __shared__ uint8_t  scnt[28];
    __shared__ uint16_t soff[29];
    __shared__ uint32_t slist[28 * 12];

    if (tid < 28) scnt[tid] = cnt[(size_t)b * IMG + x0 + tid];
    __syncthreads();
    if (tid == 0) {
        uint16_t acc = 0;
        #pragma unroll
        for (int i = 0; i < 28; ++i) { soff[i] = acc; acc += scnt[i]; }
        soff[28] = acc;
    }
    __syncthreads();

    for (int e = tid; e < 28 * 12; e += 128) {
        const int xl = e / 12;
        const int j  = e - xl * 12;
        if (j < (int)scnt[xl]) {
            const uint32_t raw = runs[((size_t)b * IMG + x0 + xl) * 32 + j]; // bits 0..16
            slist[soff[xl] + j] = raw | ((uint32_t)xl << 17);
        }
    }
    __syncthreads();

    const int total = soff[28];
    const uint32_t* Pbase = P32 + (size_t)x0 * 225 * 128 + tid;
    float a0 = 0.0f, a1 = 0.0f, b0 = 0.0f, b1 = 0.0f;
    int i = 0;
    for (; i + 2 <= total; i += 2) {
        const uint32_t e0 = slist[i];
        const uint32_t e1 = slist[i + 1];
        const uint32_t* px0 = Pbase + (size_t)(e0 >> 17) * (225 * 128);
        const uint32_t* px1 = Pbase + (size_t)(e1 >> 17) * (225 * 128);
        const uint32_t va0 = px0[(size_t)(e0 & 255u) * 128];
        const uint32_t vc0 = px0[(size_t)((e0 >> 8) & 511u) * 128];
        const uint32_t va1 = px1[(size_t)(e1 & 255u) * 128];
        const uint32_t vc1 = px1[(size_t)((e1 >> 8) & 511u) * 128];
        a0 += __uint_as_float(vc0 << 16) - __uint_as_float(va0 << 16);
        a1 += __uint_as_float(vc0 & 0xffff0000u) - __uint_as_float(va0 & 0xffff0000u);
        b0 += __uint_as_float(vc1 << 16) - __uint_as_float(va1 << 16);
        b1 += __uint_as_float(vc1 & 0xffff0000u) - __uint_as_float(va1 & 0xffff0000u);
    }
    if (i < total) {
        const uint32_t e0 = slist[i];
        const uint32_t* px0 = Pbase + (size_t)(e0 >> 17) * (225 * 128);
        const uint32_t va0 = px0[(size_t)(e0 & 255u) * 128];
        const uint32_t vc0 = px0[(size_t)((e0 >> 8) & 511u) * 128];
        a0 += __uint_as_float(vc0 << 16) - __uint_as_float(va0 << 16);
        a1 += __uint_as_float(vc0 & 0xffff0000u) - __uint_as_float(va0 & 0xffff0000u);
    }

    float* pp = part + (((size_t)b * 8 + s) * 256) + (size_t)tid * 2;
    pp[0] = a0 + b0;
    pp[1] = a1 + b1;
}

// ---------------- K4: out = rgb * (bias + sum of partials) -------------------
__global__ void k_final(const float* __restrict__ rgb, const float* __restrict__ bias,
                        const float* __restrict__ part, float* __restrict__ out) {
    const int idx = blockIdx.x * 256 + threadIdx.x;
    const int b = idx >> 8, o = idx & 255;
    float m = bias[o];
    #pragma unroll
    for (int s = 0; s < 8; ++s) m += part[(((size_t)b * 8 + s) * 256) + o];
    out[idx] = rgb[idx] * m;
}

extern "C" void kernel_launch(void* const* d_in, const int* in_sizes, int n_in,
                              void* d_out, int out_size, void* d_ws, size_t ws_size,
                              hipStream_t stream) {
    const float* rgb  = (const float*)d_in[0];
    const float* skel = (const float*)d_in[1];
    const float* W    = (const float*)d_in[2];
    const float* bias = (const float*)d_in[3];
    float* out = (float*)d_out;

    uint8_t* ws = (uint8_t*)d_ws;
    __hip_bfloat16* P = (__hip_bfloat16*)(ws);
    uint32_t* runs = (uint32_t*)(ws + OFF_RUNS);
    float* part = (float*)(ws + OFF_PART);
    uint8_t* cnt = (uint8_t*)(ws + OFF_CNT);

    KA<<<dim3(2048), dim3(256), 0, stream>>>(W, P, skel, runs, cnt);
    k_accum<<<dim3(BATCH * 8), dim3(128), 0, stream>>>(runs, cnt, (const uint32_t*)P, part);
    k_final<<<dim3(BATCH), dim3(256), 0, stream>>>(rgb, bias, part, out);
}

// Round 8
// 41.763 us; speedup vs baseline: 9.1339x; 1.0878x over previous
//
#include <hip/hip_runtime.h>
#include <hip/hip_bf16.h>
#include <stdint.h>

#define IMG   224
#define OUTD  256
#define BATCH 256
#define JD    25
#define TD    64
#define MIDJ  12
#define BOXR  20

typedef float vfloat4 __attribute__((ext_vector_type(4)));  // clang vector: OK for nontemporal builtins

// workspace layout (bytes)
//   P      : bf16 [224][225][256]   = 25,804,800
//   evlist : u32  [256*8][256]      =  2,097,152  (<=168 used per (b,slice))
//   evcnt  : u32  [256*8]           =      8,192
//   part   : f32  [256][8][256]     =  2,097,152
#define OFF_EV   25804800u
#define OFF_EVC  27901952u
#define OFF_PART 27910144u

// NOTE (r4/r5): NO device-scope fences / coop grid sync inside kernels — on
// gfx950 an agent-scope release forces an L2 writeback per issuing block
// (per-XCD L2s non-coherent); cost 70-300us. Kernel boundaries give the same
// visibility with one amortized flush.

// ======= KA: fused wpref (blocks 0..895) + boxes/events (896..1151), 512t ===
// wpref: id&7 == x/28 == slice s, so (round-robin dispatch) the XCD that
// writes P slice s is the XCD whose k_accum slice-s blocks read it.
// W loads: nontemporal vfloat4 (W read exactly once; 1KB/wave-instr).
// boxes: emits compact per-(b,slice) event lists consumed by k_accum.
__global__ void KA(const float* __restrict__ W, __hip_bfloat16* __restrict__ P,
                   const float* __restrict__ skel, uint32_t* __restrict__ evlist,
                   uint32_t* __restrict__ evcnt) {
    const int id  = blockIdx.x;
    const int tid = threadIdx.x;        // 0..511

    __shared__ float lds[64][225];      // wpref: [o_local][y]; stride 225: scan
    __shared__ float carry[8][64];      //   phase bank = (ol+y)%32, 2-way free
    __shared__ int s_px[JD], s_ylo[JD], s_yhi[JD];
    __shared__ uint32_t s_n[IMG];

    if (id < 896) {
        // ---------------- wpref ----------------
        const int xcd = id & 7;
        const int g   = id >> 3;        // 0..111
        const int oc  = g & 3;
        const int xi  = g >> 2;         // 0..27
        const int x   = xcd * 28 + xi;
        const int o0  = oc * 64;

        // vfloat4 loads: 64 rows x 56 float4; 3584 / 512 = 7 per thread
        #pragma unroll
        for (int it = 0; it < 7; ++it) {
            const int k = it * 512 + tid;
            const int r = k / 56;
            const int c = k - r * 56;
            const vfloat4 v = __builtin_nontemporal_load(
                (const vfloat4*)&W[(size_t)(o0 + r) * (IMG * IMG) + (size_t)x * IMG + c * 4]);
            lds[r][c * 4 + 0] = v.x;
            lds[r][c * 4 + 1] = v.y;
            lds[r][c * 4 + 2] = v.z;
            lds[r][c * 4 + 3] = v.w;
        }
        __syncthreads();

        const int ol  = tid & 63;       // o_local 0..63
        const int seg = tid >> 6;       // 0..7, owns y in [seg*28, seg*28+28)
        const int y0  = seg * 28;

        float ssum = 0.0f;
        #pragma unroll
        for (int i = 0; i < 28; ++i) ssum += lds[ol][y0 + i];
        carry[seg][ol] = ssum;
        __syncthreads();

        float s = 0.0f;
        for (int s2 = 0; s2 < seg; ++s2) s += carry[s2][ol];

        __hip_bfloat16* p = P + ((size_t)x * 225) * 256 + o0 + ol;
        if (seg == 0) p[0] = __float2bfloat16(0.0f);
        #pragma unroll
        for (int i = 0; i < 28; ++i) {
            s += lds[ol][y0 + i];
            p[(size_t)(y0 + i + 1) * 256] = __float2bfloat16(s);  // 128B/wave
        }
        return;
    }

    // ---------------- boxes/events (one block per batch) ----------------
    const int b = id - 896;
    const int wave = tid >> 6;          // 0..7
    const int t = tid & 63;

    const float* sb = skel + (size_t)b * JD * TD * 3;
    const float mx = sb[(MIDJ * TD + t) * 3 + 0];
    const float my = sb[(MIDJ * TD + t) * 3 + 1];
    const float mz = sb[(MIDJ * TD + t) * 3 + 2];

    for (int j = wave; j < JD; j += 8) {
        const float ax = sb[(j * TD + t) * 3 + 0];
        const float ay = sb[(j * TD + t) * 3 + 1];
        const float az = sb[(j * TD + t) * 3 + 2];
        const float dx = ax - mx, dy = ay - my, dz = az - mz;
        // match numpy: no fma contraction, left-to-right adds, IEEE sqrt
        const float d2 = __fadd_rn(__fadd_rn(__fmul_rn(dx, dx), __fmul_rn(dy, dy)),
                                   __fmul_rn(dz, dz));
        float bd = sqrtf(d2);
        int   bi = t;
        #pragma unroll
        for (int off = 1; off < 64; off <<= 1) {
            const float od = __shfl_xor(bd, off);
            const int   oi = __shfl_xor(bi, off);
            if (od > bd || (od == bd && oi < bi)) { bd = od; bi = oi; }
        }
        if (t == 0) {
            const float ptx = sb[(j * TD + bi) * 3 + 0];
            const float pty = sb[(j * TD + bi) * 3 + 1];
            const int px = (int)(ptx * 224.0f);
            const int py = (int)(pty * 224.0f);
            s_px[j]  = px;
            s_ylo[j] = (py < BOXR) ? 0 : (py - BOXR);
            s_yhi[j] = (py > IMG - BOXR) ? IMG : (py + BOXR);
        }
    }
    __syncthreads();

    const int x = tid;
    unsigned long long m0 = 0, m1 = 0, m2 = 0, m3 = 0;
    uint32_t n = 0;
    if (x < IMG) {
        for (int j = 0; j < JD; ++j) {
            if (j == MIDJ) continue;
            const int px = s_px[j];
            if (x >= px - BOXR && x < px + BOXR) {
                const int lo = s_ylo[j], hi = s_yhi[j];
                auto setw = [&](unsigned long long& mw, int wbase) {
                    int l = lo - wbase; int h = hi - wbase;
                    l = l < 0 ? 0 : l; h = h > 64 ? 64 : h;
                    if (l < h) {
                        unsigned long long msk =
                            (h - l == 64) ? ~0ull : ((((1ull << (h - l)) - 1ull)) << l);
                        mw |= msk;
                    }
                };
                setw(m0, 0); setw(m1, 64); setw(m2, 128); setw(m3, 192);
            }
        }
        // run count = number of rising edges in the 224-bit mask
        const unsigned long long e0 = m0 & ~(m0 << 1);
        const unsigned long long e1 = m1 & ~((m1 << 1) | (m0 >> 63));
        const unsigned long long e2 = m2 & ~((m2 << 1) | (m1 >> 63));
        const unsigned long long e3 = m3 & ~((m3 << 1) | (m2 >> 63));
        n = (uint32_t)(__popcll(e0) + __popcll(e1) + __popcll(e2) + __popcll(e3));
        s_n[x] = n;
    }
    __syncthreads();
    if (x >= IMG) return;

    const int sl = x / 28;              // slice
    const int xl = x - sl * 28;         // x within slice
    uint32_t off = 0;
    for (int i = sl * 28; i < x; ++i) off += s_n[i];
    if (xl == 27) evcnt[(size_t)b * 8 + sl] = off + n;

    // emit events: ev = xl | (start<<5) | (end<<13)   (end<=224 fits 8 bits)
    uint32_t* evs = evlist + ((size_t)b * 8 + sl) * 256 + off;
    int k = 0, start = -1;
    auto scanw = [&](unsigned long long bits, int wbase) {
        int pos = 0;
        while (pos < 64) {
            if (start < 0) {
                const unsigned long long tt = bits >> pos;
                if (!tt) return;
                pos += __builtin_ctzll(tt);
                start = wbase + pos;
            } else {
                const unsigned long long tt = (~bits) >> pos;
                if (!tt) return;
                pos += __builtin_ctzll(tt);
                evs[k] = (uint32_t)xl | ((uint32_t)start << 5)
                                      | ((uint32_t)(wbase + pos) << 13);
                ++k; start = -1;
            }
        }
    };
    scanw(m0, 0); scanw(m1, 64); scanw(m2, 128); scanw(m3, 192);
    if (start >= 0) { evs[k] = (uint32_t)xl | ((uint32_t)start << 5) | (224u << 13); }
}

// ---------------- k_accum: run endpoint diffs over prefix table --------------
// One round trip for count (broadcast) + event list (coalesced, loaded
// unconditionally, masked by count); phase C 4-way unrolled -> 8 loads in
// flight per wave. blockIdx = b*8+s puts slice s on XCD s, matching KA's P
// placement so P columns are L2-shared across the ~256 blocks of a slice.
__global__ void k_accum(const uint32_t* __restrict__ evlist,
                        const uint32_t* __restrict__ evcnt,
                        const uint32_t* __restrict__ P32,   // P viewed as bf16x2
                        float* __restrict__ part) {
    const int bs  = blockIdx.x;         // b*8 + s
    const int s   = bs & 7;
    const int tid = threadIdx.x;        // 0..127 -> outputs 2*tid, 2*tid+1
    const int x0  = s * 28;

    __shared__ uint32_t slist[256];

    const uint32_t cntv = evcnt[bs];                      // broadcast load
    slist[tid]       = evlist[(size_t)bs * 256 + tid];    // independent of cntv
    slist[128 + tid] = evlist[(size_t)bs * 256 + 128 + tid];
    __syncthreads();

    const int total = (int)cntv;
    const uint32_t* Pbase = P32 + (size_t)x0 * (225 * 128) + tid;

    float a0 = 0.f, a1 = 0.f, b0 = 0.f, b1 = 0.f;
    float c0 = 0.f, c1 = 0.f, d0 = 0.f, d1 = 0.f;
    int i = 0;
    for (; i + 4 <= total; i += 4) {
        const uint32_t e0 = slist[i], e1 = slist[i + 1];
        const uint32_t e2 = slist[i + 2], e3 = slist[i + 3];
        const uint32_t* p0 = Pbase + (size_t)(e0 & 31u) * (225 * 128);
        const uint32_t* p1 = Pbase + (size_t)(e1 & 31u) * (225 * 128);
        const uint32_t* p2 = Pbase + (size_t)(e2 & 31u) * (225 * 128);
        const uint32_t* p3 = Pbase + (size_t)(e3 & 31u) * (225 * 128);
        const uint32_t va0 = p0[(size_t)((e0 >> 5) & 255u) * 128];
        const uint32_t vc0 = p0[(size_t)((e0 >> 13) & 255u) * 128];
        const uint32_t va1 = p1[(size_t)((e1 >> 5) & 255u) * 128];
        const uint32_t vc1 = p1[(size_t)((e1 >> 13) & 255u) * 128];
        const uint32_t va2 = p2[(size_t)((e2 >> 5) & 255u) * 128];
        const uint32_t vc2 = p2[(size_t)((e2 >> 13) & 255u) * 128];
        const uint32_t va3 = p3[(size_t)((e3 >> 5) & 255u) * 128];
        const uint32_t vc3 = p3[(size_t)((e3 >> 13) & 255u) * 128];
        a0 += __uint_as_float(vc0 << 16) - __uint_as_float(va0 << 16);
        a1 += __uint_as_float(vc0 & 0xffff0000u) - __uint_as_float(va0 & 0xffff0000u);
        b0 += __uint_as_float(vc1 << 16) - __uint_as_float(va1 << 16);
        b1 += __uint_as_float(vc1 & 0xffff0000u) - __uint_as_float(va1 & 0xffff0000u);
        c0 += __uint_as_float(vc2 << 16) - __uint_as_float(va2 << 16);
        c1 += __uint_as_float(vc2 & 0xffff0000u) - __uint_as_float(va2 & 0xffff0000u);
        d0 += __uint_as_float(vc3 << 16) - __uint_as_float(va3 << 16);
        d1 += __uint_as_float(vc3 & 0xffff0000u) - __uint_as_float(va3 & 0xffff0000u);
    }
    for (; i < total; ++i) {
        const uint32_t e0 = slist[i];
        const uint32_t* p0 = Pbase + (size_t)(e0 & 31u) * (225 * 128);
        const uint32_t va0 = p0[(size_t)((e0 >> 5) & 255u) * 128];
        const uint32_t vc0 = p0[(size_t)((e0 >> 13) & 255u) * 128];
        a0 += __uint_as_float(vc0 << 16) - __uint_as_float(va0 << 16);
        a1 += __uint_as_float(vc0 & 0xffff0000u) - __uint_as_float(va0 & 0xffff0000u);
    }

    float* pp = part + ((size_t)bs * 256) + (size_t)tid * 2;
    pp[0] = (a0 + b0) + (c0 + d0);
    pp[1] = (a1 + b1) + (c1 + d1);
}

// ---------------- k_final: out = rgb * (bias + sum of partials) --------------
__global__ void k_final(const float* __restrict__ rgb, const float* __restrict__ bias,
                        const float* __restrict__ part, float* __restrict__ out) {
    const int idx = blockIdx.x * 256 + threadIdx.x;
    const int b = idx >> 8, o = idx & 255;
    float m = bias[o];
    #pragma unroll
    for (int s = 0; s < 8; ++s) m += part[(((size_t)b * 8 + s) * 256) + o];
    out[idx] = rgb[idx] * m;
}

extern "C" void kernel_launch(void* const* d_in, const int* in_sizes, int n_in,
                              void* d_out, int out_size, void* d_ws, size_t ws_size,
                              hipStream_t stream) {
    const float* rgb  = (const float*)d_in[0];
    const float* skel = (const float*)d_in[1];
    const float* W    = (const float*)d_in[2];
    const float* bias = (const float*)d_in[3];
    float* out = (float*)d_out;

    uint8_t* ws = (uint8_t*)d_ws;
    __hip_bfloat16* P = (__hip_bfloat16*)(ws);
    uint32_t* evlist = (uint32_t*)(ws + OFF_EV);
    uint32_t* evcnt  = (uint32_t*)(ws + OFF_EVC);
    float* part = (float*)(ws + OFF_PART);

    KA<<<dim3(1152), dim3(512), 0, stream>>>(W, P, skel, evlist, evcnt);
    k_accum<<<dim3(BATCH * 8), dim3(128), 0, stream>>>(evlist, evcnt, (const uint32_t*)P, part);
    k_final<<<dim3(BATCH), dim3(256), 0, stream>>>(rgb, bias, part, out);
}

// Round 9
// 40.098 us; speedup vs baseline: 9.5131x; 1.0415x over previous
//
#include <hip/hip_runtime.h>
#include <hip/hip_bf16.h>
#include <stdint.h>

#define IMG   224
#define OUTD  256
#define BATCH 256
#define JD    25
#define TD    64
#define MIDJ  12
#define BOXR  20
#define NSL   16           // x-slices of 14
#define SLW   14

typedef float vfloat4 __attribute__((ext_vector_type(4)));

// workspace layout (bytes)
//   P      : bf16 [224][225][256]   = 25,804,800
//   evlist : u32  [256*16][256]     =  4,194,304  (<=168 used per (b,slice))
//   evcnt  : u32  [256*16]          =     16,384
//   part   : f32  [256][16][256]    =  4,194,304
#define OFF_EV   25804800u
#define OFF_EVC  29999104u
#define OFF_PART 30015488u

// NOTE (r4/r5): NO device-scope fences / coop grid sync inside kernels — on
// gfx950 an agent-scope release forces an L2 writeback per issuing block
// (per-XCD L2s non-coherent); cost 70-300us. Kernel boundaries give the same
// visibility with one amortized flush. (r8): per-dispatch acquire also
// INVALIDATES L2, so cross-kernel L2 reuse of P is impossible — k_accum's
// endpoint reads come from L3; optimize for L3 latency/BW, not L2 locality.

// ======= KA: fused wpref (blocks 0..895) + boxes/events (896..1151), 512t ===
__global__ void KA(const float* __restrict__ W, __hip_bfloat16* __restrict__ P,
                   const float* __restrict__ skel, uint32_t* __restrict__ evlist,
                   uint32_t* __restrict__ evcnt) {
    const int id  = blockIdx.x;
    const int tid = threadIdx.x;        // 0..511

    __shared__ float lds[64][225];      // wpref: [o_local][y]; stride 225 keeps
    __shared__ float carry[8][64];      //   scan-phase reads conflict-free
    __shared__ int s_px[JD], s_ylo[JD], s_yhi[JD];
    __shared__ uint32_t s_n[IMG];

    if (id < 896) {
        // ---------------- wpref ----------------
        const int xcd = id & 7;         // low 3 bits of 16-slice index
        const int r   = id >> 3;        // 0..111
        const int oc  = r & 3;
        const int q   = r >> 2;         // 0..27
        const int xi  = q % 14;
        const int hi8 = q / 14;         // 0..1
        const int x   = (hi8 * 8 + xcd) * SLW + xi;   // (x/14)%8 == id%8
        const int o0  = oc * 64;

        // vfloat4 nontemporal loads: 64 rows x 56 float4; 3584/512 = 7/thread
        #pragma unroll
        for (int it = 0; it < 7; ++it) {
            const int k = it * 512 + tid;
            const int rr = k / 56;
            const int c  = k - rr * 56;
            const vfloat4 v = __builtin_nontemporal_load(
                (const vfloat4*)&W[(size_t)(o0 + rr) * (IMG * IMG) + (size_t)x * IMG + c * 4]);
            lds[rr][c * 4 + 0] = v.x;
            lds[rr][c * 4 + 1] = v.y;
            lds[rr][c * 4 + 2] = v.z;
            lds[rr][c * 4 + 3] = v.w;
        }
        __syncthreads();

        const int ol  = tid & 63;       // o_local 0..63
        const int seg = tid >> 6;       // 0..7, owns y in [seg*28, seg*28+28)
        const int y0  = seg * 28;

        // register-resident scan: read each element ONCE (r8: was read twice)
        float rv[28];
        #pragma unroll
        for (int i = 0; i < 28; ++i) rv[i] = lds[ol][y0 + i];

        float ssum = 0.0f;
        #pragma unroll
        for (int i = 0; i < 28; ++i) ssum += rv[i];
        carry[seg][ol] = ssum;
        __syncthreads();

        float s = 0.0f;
        for (int s2 = 0; s2 < seg; ++s2) s += carry[s2][ol];

        __hip_bfloat16* p = P + ((size_t)x * 225) * 256 + o0 + ol;
        if (seg == 0) p[0] = __float2bfloat16(0.0f);
        #pragma unroll
        for (int i = 0; i < 28; ++i) {
            s += rv[i];
            p[(size_t)(y0 + i + 1) * 256] = __float2bfloat16(s);  // 128B/wave
        }
        return;
    }

    // ---------------- boxes/events (one block per batch) ----------------
    const int b = id - 896;
    const int wave = tid >> 6;          // 0..7
    const int t = tid & 63;

    const float* sb = skel + (size_t)b * JD * TD * 3;
    const float mx = sb[(MIDJ * TD + t) * 3 + 0];
    const float my = sb[(MIDJ * TD + t) * 3 + 1];
    const float mz = sb[(MIDJ * TD + t) * 3 + 2];

    for (int j = wave; j < JD; j += 8) {
        const float ax = sb[(j * TD + t) * 3 + 0];
        const float ay = sb[(j * TD + t) * 3 + 1];
        const float az = sb[(j * TD + t) * 3 + 2];
        const float dx = ax - mx, dy = ay - my, dz = az - mz;
        // match numpy: no fma contraction, left-to-right adds, IEEE sqrt
        const float d2 = __fadd_rn(__fadd_rn(__fmul_rn(dx, dx), __fmul_rn(dy, dy)),
                                   __fmul_rn(dz, dz));
        float bd = sqrtf(d2);
        int   bi = t;
        #pragma unroll
        for (int off = 1; off < 64; off <<= 1) {
            const float od = __shfl_xor(bd, off);
            const int   oi = __shfl_xor(bi, off);
            if (od > bd || (od == bd && oi < bi)) { bd = od; bi = oi; }
        }
        if (t == 0) {
            const float ptx = sb[(j * TD + bi) * 3 + 0];
            const float pty = sb[(j * TD + bi) * 3 + 1];
            const int px = (int)(ptx * 224.0f);
            const int py = (int)(pty * 224.0f);
            s_px[j]  = px;
            s_ylo[j] = (py < BOXR) ? 0 : (py - BOXR);
            s_yhi[j] = (py > IMG - BOXR) ? IMG : (py + BOXR);
        }
    }
    __syncthreads();

    const int x = tid;
    unsigned long long m0 = 0, m1 = 0, m2 = 0, m3 = 0;
    uint32_t n = 0;
    if (x < IMG) {
        for (int j = 0; j < JD; ++j) {
            if (j == MIDJ) continue;
            const int px = s_px[j];
            if (x >= px - BOXR && x < px + BOXR) {
                const int lo = s_ylo[j], hi = s_yhi[j];
                auto setw = [&](unsigned long long& mw, int wbase) {
                    int l = lo - wbase; int h = hi - wbase;
                    l = l < 0 ? 0 : l; h = h > 64 ? 64 : h;
                    if (l < h) {
                        unsigned long long msk =
                            (h - l == 64) ? ~0ull : ((((1ull << (h - l)) - 1ull)) << l);
                        mw |= msk;
                    }
                };
                setw(m0, 0); setw(m1, 64); setw(m2, 128); setw(m3, 192);
            }
        }
        // run count = rising edges of the 224-bit mask
        const unsigned long long e0 = m0 & ~(m0 << 1);
        const unsigned long long e1 = m1 & ~((m1 << 1) | (m0 >> 63));
        const unsigned long long e2 = m2 & ~((m2 << 1) | (m1 >> 63));
        const unsigned long long e3 = m3 & ~((m3 << 1) | (m2 >> 63));
        n = (uint32_t)(__popcll(e0) + __popcll(e1) + __popcll(e2) + __popcll(e3));
        s_n[x] = n;
    }
    __syncthreads();
    if (x >= IMG) return;

    const int sl = x / SLW;             // slice 0..15
    const int xl = x - sl * SLW;        // 0..13
    uint32_t off = 0;
    for (int i = sl * SLW; i < x; ++i) off += s_n[i];
    if (xl == SLW - 1) evcnt[(size_t)b * NSL + sl] = off + n;

    // emit events: ev = xl | (start<<5) | (end<<13)
    uint32_t* evs = evlist + ((size_t)b * NSL + sl) * 256 + off;
    int k = 0, start = -1;
    auto scanw = [&](unsigned long long bits, int wbase) {
        int pos = 0;
        while (pos < 64) {
            if (start < 0) {
                const unsigned long long tt = bits >> pos;
                if (!tt) return;
                pos += __builtin_ctzll(tt);
                start = wbase + pos;
            } else {
                const unsigned long long tt = (~bits) >> pos;
                if (!tt) return;
                pos += __builtin_ctzll(tt);
                evs[k] = (uint32_t)xl | ((uint32_t)start << 5)
                                      | ((uint32_t)(wbase + pos) << 13);
                ++k; start = -1;
            }
        }
    };
    scanw(m0, 0); scanw(m1, 64); scanw(m2, 128); scanw(m3, 192);
    if (start >= 0) { evs[k] = (uint32_t)xl | ((uint32_t)start << 5) | (224u << 13); }
}

// ---------------- k_accum: run endpoint diffs over prefix table --------------
// L3-latency-bound: 16 slices -> 4096 blocks (16/CU, 32 waves/CU = max occ),
// 8-way unroll -> 16 independent loads in flight per wave.
__global__ void k_accum(const uint32_t* __restrict__ evlist,
                        const uint32_t* __restrict__ evcnt,
                        const uint32_t* __restrict__ P32,   // P viewed as bf16x2
                        float* __restrict__ part) {
    const int bs  = blockIdx.x;         // b*16 + s
    const int s   = bs & (NSL - 1);
    const int tid = threadIdx.x;        // 0..127 -> outputs 2*tid, 2*tid+1
    const int x0  = s * SLW;

    __shared__ uint32_t slist[256];

    const uint32_t cntv = evcnt[bs];                      // broadcast load
    slist[tid]       = evlist[(size_t)bs * 256 + tid];    // independent of cntv
    slist[128 + tid] = evlist[(size_t)bs * 256 + 128 + tid];
    __syncthreads();

    const int total = (int)cntv;
    const uint32_t* Pbase = P32 + (size_t)x0 * (225 * 128) + tid;

    float aLo[8] = {0.f,0.f,0.f,0.f,0.f,0.f,0.f,0.f};
    float aHi[8] = {0.f,0.f,0.f,0.f,0.f,0.f,0.f,0.f};
    int i = 0;
    for (; i + 8 <= total; i += 8) {
        uint32_t ev[8], va[8], vc[8];
        #pragma unroll
        for (int u = 0; u < 8; ++u) ev[u] = slist[i + u];
        #pragma unroll
        for (int u = 0; u < 8; ++u) {
            const uint32_t* p = Pbase + (size_t)(ev[u] & 31u) * (225 * 128);
            va[u] = p[(size_t)((ev[u] >> 5) & 255u) * 128];
            vc[u] = p[(size_t)((ev[u] >> 13) & 255u) * 128];
        }
        #pragma unroll
        for (int u = 0; u < 8; ++u) {
            aLo[u] += __uint_as_float(vc[u] << 16) - __uint_as_float(va[u] << 16);
            aHi[u] += __uint_as_float(vc[u] & 0xffff0000u) - __uint_as_float(va[u] & 0xffff0000u);
        }
    }
    for (; i < total; ++i) {
        const uint32_t e0 = slist[i];
        const uint32_t* p0 = Pbase + (size_t)(e0 & 31u) * (225 * 128);
        const uint32_t va0 = p0[(size_t)((e0 >> 5) & 255u) * 128];
        const uint32_t vc0 = p0[(size_t)((e0 >> 13) & 255u) * 128];
        aLo[0] += __uint_as_float(vc0 << 16) - __uint_as_float(va0 << 16);
        aHi[0] += __uint_as_float(vc0 & 0xffff0000u) - __uint_as_float(va0 & 0xffff0000u);
    }

    // fixed pairwise reduction order -> deterministic
    const float lo = ((aLo[0] + aLo[1]) + (aLo[2] + aLo[3]))
                   + ((aLo[4] + aLo[5]) + (aLo[6] + aLo[7]));
    const float hi = ((aHi[0] + aHi[1]) + (aHi[2] + aHi[3]))
                   + ((aHi[4] + aHi[5]) + (aHi[6] + aHi[7]));

    float* pp = part + ((size_t)bs * 256) + (size_t)tid * 2;
    pp[0] = lo;
    pp[1] = hi;
}

// ---------------- k_final: out = rgb * (bias + sum of partials) --------------
__global__ void k_final(const float* __restrict__ rgb, const float* __restrict__ bias,
                        const float* __restrict__ part, float* __restrict__ out) {
    const int idx = blockIdx.x * 256 + threadIdx.x;
    const int b = idx >> 8, o = idx & 255;
    float m = bias[o];
    #pragma unroll
    for (int s = 0; s < NSL; ++s) m += part[(((size_t)b * NSL + s) * 256) + o];
    out[idx] = rgb[idx] * m;
}

extern "C" void kernel_launch(void* const* d_in, const int* in_sizes, int n_in,
                              void* d_out, int out_size, void* d_ws, size_t ws_size,
                              hipStream_t stream) {
    const float* rgb  = (const float*)d_in[0];
    const float* skel = (const float*)d_in[1];
    const float* W    = (const float*)d_in[2];
    const float* bias = (const float*)d_in[3];
    float* out = (float*)d_out;

    uint8_t* ws = (uint8_t*)d_ws;
    __hip_bfloat16* P = (__hip_bfloat16*)(ws);
    uint32_t* evlist = (uint32_t*)(ws + OFF_EV);
    uint32_t* evcnt  = (uint32_t*)(ws + OFF_EVC);
    float* part = (float*)(ws + OFF_PART);

    KA<<<dim3(1152), dim3(512), 0, stream>>>(W, P, skel, evlist, evcnt);
    k_accum<<<dim3(BATCH * NSL), dim3(128), 0, stream>>>(evlist, evcnt, (const uint32_t*)P, part);
    k_final<<<dim3(BATCH), dim3(256), 0, stream>>>(rgb, bias, part, out);
}